// Round 1
// baseline (989.532 us; speedup 1.0000x reference)
//
#include <hip/hip_runtime.h>
#include <hip/hip_bf16.h>

#define NN 50000
#define EE 800000
#define DIN 1433
#define KTOT 1432
#define EPSC 1e-7f
#define MINN 1e-15f
#define MAXN 1e6f

// workspace layout (float offsets)
#define WT_OFF   0
#define Z1A_OFF  91648
#define Z1B_OFF  (Z1A_OFF + 3200000)
#define SUP1_OFF (Z1B_OFF + 3200000)
#define SUP2_OFF (SUP1_OFF + 3200000)
#define XT3_OFF  (SUP2_OFF + 400000)
// total floats = XT3_OFF + 400000 = 10,491,648  (~42 MB)

__device__ __forceinline__ float wsum(float v) {
#pragma unroll
  for (int o = 1; o < 64; o <<= 1) v += __shfl_xor(v, o, 64);
  return v;
}

// Computes logmap0(proj(mobius_add(proj(expmap0(z)), hyp_bias(b)))) for one node.
// lane j holds component j; spatial components are lanes 1..D-1; returns 0 on other lanes.
__device__ float hyp_linear_chain(float z, const float* b, int lane, int D) {
  const bool sp = (lane >= 1) && (lane < D);
  // mv = expmap0(z)
  float s = sp ? z : 0.f;
  float r = fmaxf(sqrtf(wsum(s * s)), MINN);
  float sh = sinhf(r);
  float y = sp ? sh * s / r : 0.f;             // spatial of res (proj keeps spatial)
  // res = proj(mv): time coord recomputed from spatial
  float yn2 = wsum(y * y);
  float x0 = sqrtf(fmaxf(1.f + yn2, EPSC));
  // u = logmap0(proj(expmap0(proj_tan0(b))))
  float bsp = sp ? b[lane] : 0.f;
  float rb = fmaxf(sqrtf(wsum(bsp * bsp)), MINN);
  float bsh = sinhf(rb);
  float hb = sp ? bsh * bsp / rb : 0.f;
  float hbn2 = wsum(hb * hb);
  float hb0 = sqrtf(fmaxf(1.f + hbn2, EPSC));
  float hbyn = fmaxf(sqrtf(hbn2), MINN);
  float u = sp ? acoshf(fmaxf(hb0, 1.f + EPSC)) * hb / hbyn : 0.f;
  // ptransp0(res, u) -> tangent vt at res
  float y_norm = fmaxf(sqrtf(yn2), MINN);
  float ynv = sp ? y / y_norm : 0.f;
  float alpha = wsum(ynv * u);
  float wsp = sp ? u - alpha * (1.f - x0) * ynv : 0.f;
  float ux = wsum(y * wsp);
  float v0 = ux / fmaxf(x0, EPSC);
  float vt = (lane == 0) ? v0 : wsp;           // zero on lanes >= D
  // expmap(vt, res)
  float md = wsum(vt * vt) - 2.f * v0 * v0;    // minkowski_dot(vt, vt)
  float nu = sqrtf(fmaxf(md, EPSC));
  nu = fminf(nu, MAXN);
  float th = fmaxf(nu, MINN);
  float cth = coshf(th), sth = sinhf(th);
  float resx = (lane == 0) ? x0 : y;
  float eres = cth * resx + sth * vt / th;
  // proj + logmap0
  float en2 = wsum(sp ? eres * eres : 0.f);
  float e0 = sqrtf(fmaxf(1.f + en2, EPSC));
  float eyn = fmaxf(sqrtf(en2), MINN);
  float out = sp ? acoshf(fmaxf(e0, 1.f + EPSC)) * eres / eyn : 0.f;
  return out;
}

// Computes logmap0(hyp_act(proj(expmap0(support)))) for one node (post-aggregation).
__device__ float agg_act_chain(float sin_, int lane, int D) {
  const bool sp = (lane >= 1) && (lane < D);
  float s = sp ? sin_ : 0.f;
  float r = fmaxf(sqrtf(wsum(s * s)), MINN);
  float sh = sinhf(r);
  float g = sp ? sh * s / r : 0.f;
  float gn2 = wsum(g * g);
  float g0 = sqrtf(fmaxf(1.f + gn2, EPSC));
  float gyn = fmaxf(sqrtf(gn2), MINN);
  float l = sp ? acoshf(fmaxf(g0, 1.f + EPSC)) * g / gyn : 0.f;
  float t = fmaxf(l, 0.f);                     // relu in tangent space
  float rt = fmaxf(sqrtf(wsum(t * t)), MINN);
  float sht = sinhf(rt);
  float h = sp ? sht * t / rt : 0.f;
  float hn2 = wsum(h * h);
  float h0 = sqrtf(fmaxf(1.f + hn2, EPSC));
  float hyn = fmaxf(sqrtf(hn2), MINN);
  float o = sp ? acoshf(fmaxf(h0, 1.f + EPSC)) * h / hyn : 0.f;
  return o;
}

__global__ __launch_bounds__(256) void prep_wt(const float* __restrict__ W1, float* __restrict__ Wt) {
  int idx = blockIdx.x * 256 + threadIdx.x;   // idx = kk*64 + j, kk in [0,1432)
  if (idx < KTOT * 64) {
    int kk = idx >> 6, j = idx & 63;
    Wt[idx] = W1[j * DIN + kk + 1];
  }
}

// z[i][j] = sum_{kk=0..1431} x[i*1433 + 1 + kk] * Wt[kk*64 + j]
// grid (391, 2): y-dim splits K into halves; partial sums to z1a / z1b.
__global__ __launch_bounds__(256) void gemm1(const float* __restrict__ x,
                                             const float* __restrict__ Wt,
                                             float* __restrict__ zout) {
  __shared__ float xs[64][130];   // xs[k][row], stride 130 (b64-aligned reads)
  __shared__ float wt_[64][64];
  const int tid = threadIdx.x;
  const int row0 = blockIdx.x * 128;
  const int kbase = blockIdx.y * 716;
  const int klim = kbase + 716;   // <= 1432
  const int ty = tid >> 4, tx = tid & 15;
  const int r0 = ty * 8, c0 = tx * 4;
  float* zp = zout + (size_t)blockIdx.y * 3200000;
  float acc[8][4];
#pragma unroll
  for (int i = 0; i < 8; ++i)
#pragma unroll
    for (int j = 0; j < 4; ++j) acc[i][j] = 0.f;

  for (int k0 = kbase; k0 < klim; k0 += 64) {
    {
      const int kk = tid & 63;
      const int rb = tid >> 6;
      const int gk = k0 + kk;
      const bool kok = (gk < klim);
#pragma unroll 4
      for (int i = 0; i < 32; ++i) {
        const int rr = rb * 32 + i;
        const int gr = row0 + rr;
        float v = 0.f;
        if ((gr < NN) && kok) v = x[gr * DIN + 1 + gk];
        xs[kk][rr] = v;
      }
    }
    {
      const int j = tid & 63;
      const int kb = tid >> 6;
#pragma unroll 4
      for (int i = 0; i < 16; ++i) {
        const int k = kb * 16 + i;
        const int gk = k0 + k;
        wt_[k][j] = (gk < klim) ? Wt[gk * 64 + j] : 0.f;
      }
    }
    __syncthreads();
#pragma unroll 8
    for (int k = 0; k < 64; ++k) {
      float a[8], bb[4];
      *(float2*)&a[0] = *(const float2*)&xs[k][r0];
      *(float2*)&a[2] = *(const float2*)&xs[k][r0 + 2];
      *(float2*)&a[4] = *(const float2*)&xs[k][r0 + 4];
      *(float2*)&a[6] = *(const float2*)&xs[k][r0 + 6];
      *(float4*)&bb[0] = *(const float4*)&wt_[k][c0];
#pragma unroll
      for (int i = 0; i < 8; ++i)
#pragma unroll
        for (int j = 0; j < 4; ++j) acc[i][j] = fmaf(a[i], bb[j], acc[i][j]);
    }
    __syncthreads();
  }
#pragma unroll
  for (int i = 0; i < 8; ++i) {
    const int gr = row0 + r0 + i;
    if (gr < NN) {
      float4 v = make_float4(acc[i][0], acc[i][1], acc[i][2], acc[i][3]);
      *(float4*)&zp[(size_t)gr * 64 + c0] = v;
    }
  }
}

// layer-1 per-node linear chain; writes xt1 in place of z1a (each thread touches only its own idx)
__global__ __launch_bounds__(256) void node1(const float* z1a, const float* z1b,
                                             const float* b1, float* xt) {
  const int node = blockIdx.x * 4 + (threadIdx.x >> 6);
  const int lane = threadIdx.x & 63;
  const int idx = node * 64 + lane;
  float z = z1a[idx] + z1b[idx];
  float o = hyp_linear_chain(z, b1, lane, 64);
  xt[idx] = o;
}

__global__ __launch_bounds__(256) void agg1(const float* __restrict__ xt, const int* __restrict__ row,
                                            const int* __restrict__ col, const float* __restrict__ ew,
                                            float* sup) {
  const int t = blockIdx.x * 256 + threadIdx.x;
  const int e = t >> 6;
  const int j = t & 63;
  const int c = col[e];
  const int r = row[e];
  const float w = ew[e];
  if (j != 0) {
    atomicAdd(&sup[r * 64 + j], w * xt[c * 64 + j]);
  }
}

// layer-1 post-agg chain + fused 64->7 GEMM + layer-2 linear chain
__global__ __launch_bounds__(256) void node2(const float* __restrict__ sup1, const float* __restrict__ W2,
                                             const float* __restrict__ b2, float* __restrict__ xt3) {
  const int node = blockIdx.x * 4 + (threadIdx.x >> 6);
  const int lane = threadIdx.x & 63;
  float s = sup1[node * 64 + lane];
  float xt2 = agg_act_chain(s, lane, 64);
  float z2 = 0.f;
#pragma unroll
  for (int jj = 1; jj < 7; ++jj) {
    float w = W2[jj * 64 + lane];
    float sjj = wsum(xt2 * w);
    if (lane == jj) z2 = sjj;
  }
  float o = hyp_linear_chain(z2, b2, lane, 7);
  if (lane < 8) xt3[node * 8 + lane] = o;
}

__global__ __launch_bounds__(256) void agg2(const float* __restrict__ xt3, const int* __restrict__ row,
                                            const int* __restrict__ col, const float* __restrict__ ew,
                                            float* sup) {
  const int t = blockIdx.x * 256 + threadIdx.x;
  const int e = t >> 3;
  const int j = t & 7;
  const int c = col[e];
  const int r = row[e];
  const float w = ew[e];
  if (j >= 1 && j < 7) {
    atomicAdd(&sup[r * 8 + j], w * xt3[c * 8 + j]);
  }
}

__global__ __launch_bounds__(256) void finalk(const float* __restrict__ sup2, float* __restrict__ out) {
  const int node = blockIdx.x * 4 + (threadIdx.x >> 6);
  const int lane = threadIdx.x & 63;
  float s = (lane < 8) ? sup2[node * 8 + lane] : 0.f;
  float o = agg_act_chain(s, lane, 7);
  if (lane < 7) out[node * 7 + lane] = o;   // lane 0 writes 0 (proj_tan0)
}

extern "C" void kernel_launch(void* const* d_in, const int* in_sizes, int n_in,
                              void* d_out, int out_size, void* d_ws, size_t ws_size,
                              hipStream_t stream) {
  const float* x = (const float*)d_in[0];
  const int* row = (const int*)d_in[1];
  const int* col = (const int*)d_in[2];
  const float* ew = (const float*)d_in[3];
  const float* W1 = (const float*)d_in[4];
  const float* b1 = (const float*)d_in[5];
  const float* W2 = (const float*)d_in[6];
  const float* b2 = (const float*)d_in[7];
  float* ws = (float*)d_ws;
  float* Wt = ws + WT_OFF;
  float* z1a = ws + Z1A_OFF;
  float* z1b = ws + Z1B_OFF;
  float* sup1 = ws + SUP1_OFF;
  float* sup2 = ws + SUP2_OFF;
  float* xt3 = ws + XT3_OFF;
  float* out = (float*)d_out;

  prep_wt<<<dim3(358), dim3(256), 0, stream>>>(W1, Wt);
  gemm1<<<dim3(391, 2), dim3(256), 0, stream>>>(x, Wt, z1a);
  hipMemsetAsync(sup1, 0, (size_t)(3200000 + 400000) * sizeof(float), stream);
  node1<<<dim3(12500), dim3(256), 0, stream>>>(z1a, z1b, b1, z1a);
  agg1<<<dim3(200000), dim3(256), 0, stream>>>(z1a, row, col, ew, sup1);
  node2<<<dim3(12500), dim3(256), 0, stream>>>(sup1, W2, b2, xt3);
  agg2<<<dim3(25000), dim3(256), 0, stream>>>(xt3, row, col, ew, sup2);
  finalk<<<dim3(12500), dim3(256), 0, stream>>>(sup2, out);
}

// Round 2
// 684.232 us; speedup vs baseline: 1.4462x; 1.4462x over previous
//
#include <hip/hip_runtime.h>
#include <hip/hip_bf16.h>

#define NN 50000
#define EE 800000
#define DIN 1433
#define KHALF 716
#define NKT 23          // ceil(716/32) k-tiles per half
#define EPSC 1e-7f
#define MINN 1e-15f
#define MAXN 1e6f

typedef __attribute__((ext_vector_type(8))) short bf16x8;
typedef __attribute__((ext_vector_type(4))) float f32x4;

// ---- workspace layout (float offsets) ----
#define WF_OFF     0                         // 2*23*4096 ushorts = 94208 floats
#define Z1A_OFF    94208
#define Z1B_OFF    (Z1A_OFF + 3200000)
#define XT3_OFF    (Z1B_OFF + 3200000)       // 50000*8
#define CNT_OFF    (XT3_OFF + 400000)        // 50000 ints
#define ROWPTR_OFF (CNT_OFF + 50000)         // 50001 ints
#define CUR_OFF    (ROWPTR_OFF + 50001)      // 50000 ints
#define EIDX_OFF   (CUR_OFF + 50000)         // 800000 ints
// end = 7,844,209 floats ≈ 31.4 MB

__device__ __forceinline__ float wsum(float v) {
#pragma unroll
  for (int o = 1; o < 64; o <<= 1) v += __shfl_xor(v, o, 64);
  return v;
}

__device__ __forceinline__ void split_bf(float v, unsigned int& hbits16, unsigned int& lbits16) {
  unsigned int b = __float_as_uint(v);
  unsigned int hb = b & 0xFFFF0000u;          // exact bf16 (truncate)
  float r = v - __uint_as_float(hb);          // residual
  unsigned int lb = __float_as_uint(r);
  lbits16 = (lb + 0x7FFFu + ((lb >> 16) & 1u)) >> 16;   // RNE to bf16
  hbits16 = hb >> 16;
}

// ===================== node-chain math (validated round 1) =====================
__device__ float hyp_linear_chain(float z, const float* b, int lane, int D) {
  const bool sp = (lane >= 1) && (lane < D);
  float s = sp ? z : 0.f;
  float r = fmaxf(sqrtf(wsum(s * s)), MINN);
  float sh = sinhf(r);
  float y = sp ? sh * s / r : 0.f;
  float yn2 = wsum(y * y);
  float x0 = sqrtf(fmaxf(1.f + yn2, EPSC));
  float bsp = sp ? b[lane] : 0.f;
  float rb = fmaxf(sqrtf(wsum(bsp * bsp)), MINN);
  float bsh = sinhf(rb);
  float hb = sp ? bsh * bsp / rb : 0.f;
  float hbn2 = wsum(hb * hb);
  float hb0 = sqrtf(fmaxf(1.f + hbn2, EPSC));
  float hbyn = fmaxf(sqrtf(hbn2), MINN);
  float u = sp ? acoshf(fmaxf(hb0, 1.f + EPSC)) * hb / hbyn : 0.f;
  float y_norm = fmaxf(sqrtf(yn2), MINN);
  float ynv = sp ? y / y_norm : 0.f;
  float alpha = wsum(ynv * u);
  float wsp = sp ? u - alpha * (1.f - x0) * ynv : 0.f;
  float ux = wsum(y * wsp);
  float v0 = ux / fmaxf(x0, EPSC);
  float vt = (lane == 0) ? v0 : wsp;
  float md = wsum(vt * vt) - 2.f * v0 * v0;
  float nu = sqrtf(fmaxf(md, EPSC));
  nu = fminf(nu, MAXN);
  float th = fmaxf(nu, MINN);
  float cth = coshf(th), sth = sinhf(th);
  float resx = (lane == 0) ? x0 : y;
  float eres = cth * resx + sth * vt / th;
  float en2 = wsum(sp ? eres * eres : 0.f);
  float e0 = sqrtf(fmaxf(1.f + en2, EPSC));
  float eyn = fmaxf(sqrtf(en2), MINN);
  float out = sp ? acoshf(fmaxf(e0, 1.f + EPSC)) * eres / eyn : 0.f;
  return out;
}

__device__ float agg_act_chain(float sin_, int lane, int D) {
  const bool sp = (lane >= 1) && (lane < D);
  float s = sp ? sin_ : 0.f;
  float r = fmaxf(sqrtf(wsum(s * s)), MINN);
  float sh = sinhf(r);
  float g = sp ? sh * s / r : 0.f;
  float gn2 = wsum(g * g);
  float g0 = sqrtf(fmaxf(1.f + gn2, EPSC));
  float gyn = fmaxf(sqrtf(gn2), MINN);
  float l = sp ? acoshf(fmaxf(g0, 1.f + EPSC)) * g / gyn : 0.f;
  float t = fmaxf(l, 0.f);
  float rt = fmaxf(sqrtf(wsum(t * t)), MINN);
  float sht = sinhf(rt);
  float h = sp ? sht * t / rt : 0.f;
  float hn2 = wsum(h * h);
  float h0 = sqrtf(fmaxf(1.f + hn2, EPSC));
  float hyn = fmaxf(sqrtf(hn2), MINN);
  float o = sp ? acoshf(fmaxf(h0, 1.f + EPSC)) * h / hyn : 0.f;
  return o;
}

// ===================== W1 -> MFMA-fragment-ready bf16 hi/lo =====================
// layout: wfrag[half][kt][c][lane][8] ushorts, c = type*4 + nt (type 0=hi, 1=lo)
__global__ __launch_bounds__(256) void prep_wfrag(const float* __restrict__ W1,
                                                  unsigned short* __restrict__ wfrag) {
  int idx = blockIdx.x * 256 + threadIdx.x;
  if (idx >= 2 * NKT * 8 * 64) return;
  int lane = idx & 63;
  int c = (idx >> 6) & 7;
  int rest = idx >> 9;
  int kt = rest % NKT;
  int half = rest / NKT;
  int type = c >> 2, nt = c & 3;
  int col = nt * 16 + (lane & 15);
  unsigned short vals[8];
#pragma unroll
  for (int i = 0; i < 8; ++i) {
    int lk = kt * 32 + (lane >> 4) * 8 + i;
    float wv = (lk < KHALF) ? W1[col * DIN + half * KHALF + lk + 1] : 0.f;
    unsigned int h16, l16;
    split_bf(wv, h16, l16);
    vals[i] = (unsigned short)((type == 0) ? h16 : l16);
  }
  unsigned short* dst = wfrag + (((size_t)(half * NKT + kt) * 8 + c) * 64 + lane) * 8;
#pragma unroll
  for (int i = 0; i < 8; ++i) dst[i] = vals[i];
}

// ===================== GEMM1: z[i][j] = sum_k x[i][1+k] * W1[j][1+k] ===========
// MFMA 16x16x32 bf16, hi/lo 3-term split-precision. grid (391, 2): y = K-half.
__global__ __launch_bounds__(256) void gemm_mfma(const float* __restrict__ x,
                                                 const unsigned short* __restrict__ wfrag,
                                                 float* __restrict__ zout) {
  __shared__ __align__(16) unsigned short Ah[128][40];  // 80B row stride
  __shared__ __align__(16) unsigned short Al[128][40];
  __shared__ __align__(16) unsigned short Bf[8][64][8]; // [type*4+nt][lane][8]
  const int tid = threadIdx.x;
  const int w = tid >> 6, lane = tid & 63;
  const int row0 = blockIdx.x * 128;
  const int half = blockIdx.y;
  const float* xb = x + 1 + half * KHALF;
  const unsigned short* wf = wfrag + (size_t)half * NKT * 4096;
  float* zp = zout + (size_t)half * 3200000;

  f32x4 acc[2][4];
#pragma unroll
  for (int m = 0; m < 2; ++m)
#pragma unroll
    for (int nt = 0; nt < 4; ++nt) acc[m][nt] = (f32x4){0.f, 0.f, 0.f, 0.f};

  const int lrow = tid >> 3;        // 0..31
  const int kq = (tid & 7) * 4;     // 0,4,...,28

  for (int kt = 0; kt < NKT; ++kt) {
    const int k0 = kt * 32;
    __syncthreads();  // previous compute done; LDS reusable
    if (w == 0) {     // stage B fragments (8 KB) straight to LDS
      const unsigned short* src = wf + (size_t)kt * 4096 + lane * 8;
#pragma unroll
      for (int c = 0; c < 8; ++c) {
        __builtin_amdgcn_global_load_lds(
            (const __attribute__((address_space(1))) unsigned int*)(src + c * 512),
            (__attribute__((address_space(3))) unsigned int*)(&Bf[c][0][0]),
            16, 0, 0);
      }
    }
    // stage A: 128 rows x 32 k, f32 -> bf16 hi/lo
#pragma unroll
    for (int pass = 0; pass < 4; ++pass) {
      int r = lrow + pass * 32;
      int gr = row0 + r;
      float v[4];
#pragma unroll
      for (int j = 0; j < 4; ++j) {
        int lk = k0 + kq + j;
        v[j] = (gr < NN && lk < KHALF) ? xb[(size_t)gr * DIN + lk] : 0.f;
      }
      unsigned int h[4], l[4];
#pragma unroll
      for (int j = 0; j < 4; ++j) split_bf(v[j], h[j], l[j]);
      uint2 hw, lw;
      hw.x = h[0] | (h[1] << 16); hw.y = h[2] | (h[3] << 16);
      lw.x = l[0] | (l[1] << 16); lw.y = l[2] | (l[3] << 16);
      *(uint2*)&Ah[r][kq] = hw;
      *(uint2*)&Al[r][kq] = lw;
    }
    __syncthreads();
    // fragments
    const int arow = w * 32 + (lane & 15);
    const int kb = (lane >> 4) * 8;
    bf16x8 ah0 = *(const bf16x8*)&Ah[arow][kb];
    bf16x8 ah1 = *(const bf16x8*)&Ah[arow + 16][kb];
    bf16x8 al0 = *(const bf16x8*)&Al[arow][kb];
    bf16x8 al1 = *(const bf16x8*)&Al[arow + 16][kb];
    bf16x8 bh[4], bl[4];
#pragma unroll
    for (int nt = 0; nt < 4; ++nt) {
      bh[nt] = *(const bf16x8*)&Bf[nt][lane][0];
      bl[nt] = *(const bf16x8*)&Bf[4 + nt][lane][0];
    }
#pragma unroll
    for (int nt = 0; nt < 4; ++nt) {
      acc[0][nt] = __builtin_amdgcn_mfma_f32_16x16x32_bf16(ah0, bh[nt], acc[0][nt], 0, 0, 0);
      acc[0][nt] = __builtin_amdgcn_mfma_f32_16x16x32_bf16(ah0, bl[nt], acc[0][nt], 0, 0, 0);
      acc[0][nt] = __builtin_amdgcn_mfma_f32_16x16x32_bf16(al0, bh[nt], acc[0][nt], 0, 0, 0);
      acc[1][nt] = __builtin_amdgcn_mfma_f32_16x16x32_bf16(ah1, bh[nt], acc[1][nt], 0, 0, 0);
      acc[1][nt] = __builtin_amdgcn_mfma_f32_16x16x32_bf16(ah1, bl[nt], acc[1][nt], 0, 0, 0);
      acc[1][nt] = __builtin_amdgcn_mfma_f32_16x16x32_bf16(al1, bh[nt], acc[1][nt], 0, 0, 0);
    }
  }
  // epilogue: D row=(lane>>4)*4+i, col=lane&15 (m89-verified)
#pragma unroll
  for (int m = 0; m < 2; ++m)
#pragma unroll
    for (int nt = 0; nt < 4; ++nt)
#pragma unroll
      for (int i = 0; i < 4; ++i) {
        int gr = row0 + w * 32 + m * 16 + (lane >> 4) * 4 + i;
        int colj = nt * 16 + (lane & 15);
        if (gr < NN) zp[(size_t)gr * 64 + colj] = acc[m][nt][i];
      }
}

// ===================== layer-1 node chain =====================
__global__ __launch_bounds__(256) void node1(const float* __restrict__ z1a,
                                             const float* __restrict__ z1b,
                                             const float* __restrict__ b1, float* xt) {
  const int node = blockIdx.x * 4 + (threadIdx.x >> 6);
  const int lane = threadIdx.x & 63;
  const int idx = node * 64 + lane;
  float z = z1a[idx] + z1b[idx];
  float o = hyp_linear_chain(z, b1, lane, 64);
  xt[idx] = o;
}

// ===================== CSR build =====================
__global__ __launch_bounds__(256) void k_hist(const int* __restrict__ row, int* __restrict__ cnt) {
  int e = blockIdx.x * 256 + threadIdx.x;
  if (e < EE) atomicAdd(&cnt[row[e]], 1);
}

__global__ __launch_bounds__(1024) void k_scan(const int* __restrict__ cnt,
                                               int* __restrict__ rowptr, int* __restrict__ cur) {
  __shared__ int ssum[1024];
  const int tid = threadIdx.x;
  const int base = tid * 49;
  int s = 0;
  for (int j = 0; j < 49; ++j) {
    int i = base + j;
    if (i < NN) s += cnt[i];
  }
  ssum[tid] = s;
  __syncthreads();
  for (int off = 1; off < 1024; off <<= 1) {
    int v = (tid >= off) ? ssum[tid - off] : 0;
    __syncthreads();
    ssum[tid] += v;
    __syncthreads();
  }
  int run = ssum[tid] - s;  // exclusive prefix of this chunk
  for (int j = 0; j < 49; ++j) {
    int i = base + j;
    if (i < NN) {
      rowptr[i] = run;
      cur[i] = run;
      run += cnt[i];
    }
  }
  if (tid == 1023) rowptr[NN] = ssum[1023];
}

__global__ __launch_bounds__(256) void k_scatter(const int* __restrict__ row,
                                                 int* __restrict__ cur, int* __restrict__ eidx) {
  int e = blockIdx.x * 256 + threadIdx.x;
  if (e < EE) {
    int p = atomicAdd(&cur[row[e]], 1);
    eidx[p] = e;
  }
}

// ===================== agg1 (gather) + act chain + W2 + layer-2 linear chain ====
__global__ __launch_bounds__(256) void agg1_node2(const int* __restrict__ rowptr,
                                                  const int* __restrict__ eidx,
                                                  const int* __restrict__ col,
                                                  const float* __restrict__ ew,
                                                  const float* __restrict__ xt,
                                                  const float* __restrict__ W2,
                                                  const float* __restrict__ b2,
                                                  float* __restrict__ xt3) {
  const int node = blockIdx.x * 4 + (threadIdx.x >> 6);
  const int lane = threadIdx.x & 63;
  const int s0 = rowptr[node], s1 = rowptr[node + 1];
  float acc = 0.f;
  for (int p = s0; p < s1; ++p) {
    int e = eidx[p];
    int c = col[e];
    float wgt = ew[e];
    acc = fmaf(wgt, xt[(size_t)c * 64 + lane], acc);
  }
  float xt2 = agg_act_chain(acc, lane, 64);
  float z2 = 0.f;
#pragma unroll
  for (int jj = 1; jj < 7; ++jj) {
    float wv = W2[jj * 64 + lane];
    float sjj = wsum(xt2 * wv);
    if (lane == jj) z2 = sjj;
  }
  float o = hyp_linear_chain(z2, b2, lane, 7);
  if (lane < 8) xt3[node * 8 + lane] = o;
}

// ===================== agg2 (gather) + final chain =====================
__global__ __launch_bounds__(256) void agg2_final(const int* __restrict__ rowptr,
                                                  const int* __restrict__ eidx,
                                                  const int* __restrict__ col,
                                                  const float* __restrict__ ew,
                                                  const float* __restrict__ xt3,
                                                  float* __restrict__ out) {
  const int node = blockIdx.x * 4 + (threadIdx.x >> 6);
  const int lane = threadIdx.x & 63;
  const int s0 = rowptr[node], s1 = rowptr[node + 1];
  float acc = 0.f;
  for (int p = s0; p < s1; ++p) {
    int e = eidx[p];
    int c = col[e];
    float wgt = ew[e];
    if (lane < 8) acc = fmaf(wgt, xt3[(size_t)c * 8 + lane], acc);
  }
  float o = agg_act_chain(acc, lane, 7);
  if (lane < 7) out[node * 7 + lane] = o;
}

extern "C" void kernel_launch(void* const* d_in, const int* in_sizes, int n_in,
                              void* d_out, int out_size, void* d_ws, size_t ws_size,
                              hipStream_t stream) {
  const float* x = (const float*)d_in[0];
  const int* row = (const int*)d_in[1];
  const int* col = (const int*)d_in[2];
  const float* ew = (const float*)d_in[3];
  const float* W1 = (const float*)d_in[4];
  const float* b1 = (const float*)d_in[5];
  const float* W2 = (const float*)d_in[6];
  const float* b2 = (const float*)d_in[7];
  float* ws = (float*)d_ws;
  unsigned short* wfrag = (unsigned short*)(ws + WF_OFF);
  float* z1a = ws + Z1A_OFF;
  float* z1b = ws + Z1B_OFF;
  float* xt3 = ws + XT3_OFF;
  int* cnt = (int*)(ws + CNT_OFF);
  int* rowptr = (int*)(ws + ROWPTR_OFF);
  int* cur = (int*)(ws + CUR_OFF);
  int* eidx = (int*)(ws + EIDX_OFF);
  float* out = (float*)d_out;

  // CSR build (independent of GEMM)
  hipMemsetAsync(cnt, 0, NN * sizeof(int), stream);
  k_hist<<<dim3(3125), dim3(256), 0, stream>>>(row, cnt);
  k_scan<<<dim3(1), dim3(1024), 0, stream>>>(cnt, rowptr, cur);
  k_scatter<<<dim3(3125), dim3(256), 0, stream>>>(row, cur, eidx);

  // layer 1 GEMM (MFMA, split-K=2)
  prep_wfrag<<<dim3(92), dim3(256), 0, stream>>>(W1, wfrag);
  gemm_mfma<<<dim3(391, 2), dim3(256), 0, stream>>>(x, wfrag, z1a);
  node1<<<dim3(12500), dim3(256), 0, stream>>>(z1a, z1b, b1, z1a);

  agg1_node2<<<dim3(12500), dim3(256), 0, stream>>>(rowptr, eidx, col, ew, z1a, W2, b2, xt3);
  agg2_final<<<dim3(12500), dim3(256), 0, stream>>>(rowptr, eidx, col, ew, xt3, out);
}

// Round 3
// 541.224 us; speedup vs baseline: 1.8283x; 1.2642x over previous
//
#include <hip/hip_runtime.h>
#include <hip/hip_bf16.h>

#define NN 50000
#define EE 800000
#define DIN 1433
#define KHALF 716
#define NKT 23          // ceil(716/32) k-tiles per half
#define EPSC 1e-7f
#define MINN 1e-15f
#define MAXN 1e6f

typedef __attribute__((ext_vector_type(8))) short bf16x8;
typedef __attribute__((ext_vector_type(4))) float f32x4;

// ---- workspace layout (float offsets) ----
#define WF_OFF     0                          // 188416 ushorts = 94208 floats
#define Z1A_OFF    94208
#define Z1B_OFF    (Z1A_OFF + 3200000)
#define XT3_OFF    (Z1B_OFF + 3200000)        // 50000*8
#define CNT_OFF    (XT3_OFF + 400000)         // 50000 ints
#define ROWPTR_OFF (CNT_OFF + 50000)          // 50002 ints (padded for ep align)
#define CUR_OFF    (ROWPTR_OFF + 50002)       // 50000 ints
#define EP_OFF     (CUR_OFF + 50000)          // 800000 uint2 = 1600000 floats (8B-aligned)
// end = 8,644,210 floats ≈ 34.6 MB

__device__ __forceinline__ float wsum(float v) {
#pragma unroll
  for (int o = 1; o < 64; o <<= 1) v += __shfl_xor(v, o, 64);
  return v;
}

__device__ __forceinline__ float gsum8(float v) {
#pragma unroll
  for (int o = 1; o < 8; o <<= 1) v += __shfl_xor(v, o, 64);
  return v;
}

__device__ __forceinline__ void split_bf(float v, unsigned int& hbits16, unsigned int& lbits16) {
  unsigned int b = __float_as_uint(v);
  unsigned int hb = b & 0xFFFF0000u;
  float r = v - __uint_as_float(hb);
  unsigned int lb = __float_as_uint(r);
  lbits16 = (lb + 0x7FFFu + ((lb >> 16) & 1u)) >> 16;
  hbits16 = hb >> 16;
}

// ===================== node-chain math (validated) =====================
__device__ float hyp_linear_chain(float z, const float* b, int lane, int D) {
  const bool sp = (lane >= 1) && (lane < D);
  float s = sp ? z : 0.f;
  float r = fmaxf(sqrtf(wsum(s * s)), MINN);
  float sh = sinhf(r);
  float y = sp ? sh * s / r : 0.f;
  float yn2 = wsum(y * y);
  float x0 = sqrtf(fmaxf(1.f + yn2, EPSC));
  float bsp = sp ? b[lane] : 0.f;
  float rb = fmaxf(sqrtf(wsum(bsp * bsp)), MINN);
  float bsh = sinhf(rb);
  float hb = sp ? bsh * bsp / rb : 0.f;
  float hbn2 = wsum(hb * hb);
  float hb0 = sqrtf(fmaxf(1.f + hbn2, EPSC));
  float hbyn = fmaxf(sqrtf(hbn2), MINN);
  float u = sp ? acoshf(fmaxf(hb0, 1.f + EPSC)) * hb / hbyn : 0.f;
  float y_norm = fmaxf(sqrtf(yn2), MINN);
  float ynv = sp ? y / y_norm : 0.f;
  float alpha = wsum(ynv * u);
  float wsp = sp ? u - alpha * (1.f - x0) * ynv : 0.f;
  float ux = wsum(y * wsp);
  float v0 = ux / fmaxf(x0, EPSC);
  float vt = (lane == 0) ? v0 : wsp;
  float md = wsum(vt * vt) - 2.f * v0 * v0;
  float nu = sqrtf(fmaxf(md, EPSC));
  nu = fminf(nu, MAXN);
  float th = fmaxf(nu, MINN);
  float cth = coshf(th), sth = sinhf(th);
  float resx = (lane == 0) ? x0 : y;
  float eres = cth * resx + sth * vt / th;
  float en2 = wsum(sp ? eres * eres : 0.f);
  float e0 = sqrtf(fmaxf(1.f + en2, EPSC));
  float eyn = fmaxf(sqrtf(en2), MINN);
  float out = sp ? acoshf(fmaxf(e0, 1.f + EPSC)) * eres / eyn : 0.f;
  return out;
}

__device__ float agg_act_chain(float sin_, int lane, int D) {
  const bool sp = (lane >= 1) && (lane < D);
  float s = sp ? sin_ : 0.f;
  float r = fmaxf(sqrtf(wsum(s * s)), MINN);
  float sh = sinhf(r);
  float g = sp ? sh * s / r : 0.f;
  float gn2 = wsum(g * g);
  float g0 = sqrtf(fmaxf(1.f + gn2, EPSC));
  float gyn = fmaxf(sqrtf(gn2), MINN);
  float l = sp ? acoshf(fmaxf(g0, 1.f + EPSC)) * g / gyn : 0.f;
  float t = fmaxf(l, 0.f);
  float rt = fmaxf(sqrtf(wsum(t * t)), MINN);
  float sht = sinhf(rt);
  float h = sp ? sht * t / rt : 0.f;
  float hn2 = wsum(h * h);
  float h0 = sqrtf(fmaxf(1.f + hn2, EPSC));
  float hyn = fmaxf(sqrtf(hn2), MINN);
  float o = sp ? acoshf(fmaxf(h0, 1.f + EPSC)) * h / hyn : 0.f;
  return o;
}

// 8-lane-group version, D=7 (for final kernel, 8 nodes per wave)
__device__ float agg_act_chain8(float sin_, int f) {
  const bool sp = (f >= 1) && (f < 7);
  float s = sp ? sin_ : 0.f;
  float r = fmaxf(sqrtf(gsum8(s * s)), MINN);
  float sh = sinhf(r);
  float g = sp ? sh * s / r : 0.f;
  float gn2 = gsum8(g * g);
  float g0 = sqrtf(fmaxf(1.f + gn2, EPSC));
  float gyn = fmaxf(sqrtf(gn2), MINN);
  float l = sp ? acoshf(fmaxf(g0, 1.f + EPSC)) * g / gyn : 0.f;
  float t = fmaxf(l, 0.f);
  float rt = fmaxf(sqrtf(gsum8(t * t)), MINN);
  float sht = sinhf(rt);
  float h = sp ? sht * t / rt : 0.f;
  float hn2 = gsum8(h * h);
  float h0 = sqrtf(fmaxf(1.f + hn2, EPSC));
  float hyn = fmaxf(sqrtf(hn2), MINN);
  float o = sp ? acoshf(fmaxf(h0, 1.f + EPSC)) * h / hyn : 0.f;
  return o;
}

// ===================== W1 -> MFMA-fragment-ready bf16 hi/lo =====================
__global__ __launch_bounds__(256) void prep_wfrag(const float* __restrict__ W1,
                                                  unsigned short* __restrict__ wfrag) {
  int idx = blockIdx.x * 256 + threadIdx.x;
  if (idx >= 2 * NKT * 8 * 64) return;
  int lane = idx & 63;
  int c = (idx >> 6) & 7;
  int rest = idx >> 9;
  int kt = rest % NKT;
  int half = rest / NKT;
  int type = c >> 2, nt = c & 3;
  int col = nt * 16 + (lane & 15);
  unsigned short vals[8];
#pragma unroll
  for (int i = 0; i < 8; ++i) {
    int lk = kt * 32 + (lane >> 4) * 8 + i;
    float wv = (lk < KHALF) ? W1[col * DIN + half * KHALF + lk + 1] : 0.f;
    unsigned int h16, l16;
    split_bf(wv, h16, l16);
    vals[i] = (unsigned short)((type == 0) ? h16 : l16);
  }
  unsigned short* dst = wfrag + (((size_t)(half * NKT + kt) * 8 + c) * 64 + lane) * 8;
#pragma unroll
  for (int i = 0; i < 8; ++i) dst[i] = vals[i];
}

// ===================== GEMM1 (MFMA bf16 hi/lo split, split-K=2) ===========
__global__ __launch_bounds__(256) void gemm_mfma(const float* __restrict__ x,
                                                 const unsigned short* __restrict__ wfrag,
                                                 float* __restrict__ zout) {
  __shared__ __align__(16) unsigned short Ah[128][40];
  __shared__ __align__(16) unsigned short Al[128][40];
  __shared__ __align__(16) unsigned short Bf[8][64][8];
  const int tid = threadIdx.x;
  const int w = tid >> 6, lane = tid & 63;
  const int row0 = blockIdx.x * 128;
  const int half = blockIdx.y;
  const float* xb = x + 1 + half * KHALF;
  const unsigned short* wf = wfrag + (size_t)half * NKT * 4096;
  float* zp = zout + (size_t)half * 3200000;

  f32x4 acc[2][4];
#pragma unroll
  for (int m = 0; m < 2; ++m)
#pragma unroll
    for (int nt = 0; nt < 4; ++nt) acc[m][nt] = (f32x4){0.f, 0.f, 0.f, 0.f};

  const int lrow = tid >> 3;
  const int kq = (tid & 7) * 4;

  for (int kt = 0; kt < NKT; ++kt) {
    const int k0 = kt * 32;
    __syncthreads();
    if (w == 0) {
      const unsigned short* src = wf + (size_t)kt * 4096 + lane * 8;
#pragma unroll
      for (int c = 0; c < 8; ++c) {
        __builtin_amdgcn_global_load_lds(
            (const __attribute__((address_space(1))) unsigned int*)(src + c * 512),
            (__attribute__((address_space(3))) unsigned int*)(&Bf[c][0][0]),
            16, 0, 0);
      }
    }
#pragma unroll
    for (int pass = 0; pass < 4; ++pass) {
      int r = lrow + pass * 32;
      int gr = row0 + r;
      float v[4];
#pragma unroll
      for (int j = 0; j < 4; ++j) {
        int lk = k0 + kq + j;
        v[j] = (gr < NN && lk < KHALF) ? xb[(size_t)gr * DIN + lk] : 0.f;
      }
      unsigned int h[4], l[4];
#pragma unroll
      for (int j = 0; j < 4; ++j) split_bf(v[j], h[j], l[j]);
      uint2 hw, lw;
      hw.x = h[0] | (h[1] << 16); hw.y = h[2] | (h[3] << 16);
      lw.x = l[0] | (l[1] << 16); lw.y = l[2] | (l[3] << 16);
      *(uint2*)&Ah[r][kq] = hw;
      *(uint2*)&Al[r][kq] = lw;
    }
    __syncthreads();
    const int arow = w * 32 + (lane & 15);
    const int kb = (lane >> 4) * 8;
    bf16x8 ah0 = *(const bf16x8*)&Ah[arow][kb];
    bf16x8 ah1 = *(const bf16x8*)&Ah[arow + 16][kb];
    bf16x8 al0 = *(const bf16x8*)&Al[arow][kb];
    bf16x8 al1 = *(const bf16x8*)&Al[arow + 16][kb];
    bf16x8 bh[4], bl[4];
#pragma unroll
    for (int nt = 0; nt < 4; ++nt) {
      bh[nt] = *(const bf16x8*)&Bf[nt][lane][0];
      bl[nt] = *(const bf16x8*)&Bf[4 + nt][lane][0];
    }
#pragma unroll
    for (int nt = 0; nt < 4; ++nt) {
      acc[0][nt] = __builtin_amdgcn_mfma_f32_16x16x32_bf16(ah0, bh[nt], acc[0][nt], 0, 0, 0);
      acc[0][nt] = __builtin_amdgcn_mfma_f32_16x16x32_bf16(ah0, bl[nt], acc[0][nt], 0, 0, 0);
      acc[0][nt] = __builtin_amdgcn_mfma_f32_16x16x32_bf16(al0, bh[nt], acc[0][nt], 0, 0, 0);
      acc[1][nt] = __builtin_amdgcn_mfma_f32_16x16x32_bf16(ah1, bh[nt], acc[1][nt], 0, 0, 0);
      acc[1][nt] = __builtin_amdgcn_mfma_f32_16x16x32_bf16(ah1, bl[nt], acc[1][nt], 0, 0, 0);
      acc[1][nt] = __builtin_amdgcn_mfma_f32_16x16x32_bf16(al1, bh[nt], acc[1][nt], 0, 0, 0);
    }
  }
#pragma unroll
  for (int m = 0; m < 2; ++m)
#pragma unroll
    for (int nt = 0; nt < 4; ++nt)
#pragma unroll
      for (int i = 0; i < 4; ++i) {
        int gr = row0 + w * 32 + m * 16 + (lane >> 4) * 4 + i;
        int colj = nt * 16 + (lane & 15);
        if (gr < NN) zp[(size_t)gr * 64 + colj] = acc[m][nt][i];
      }
}

// ===================== layer-1 node chain =====================
__global__ __launch_bounds__(256) void node1(const float* __restrict__ z1a,
                                             const float* __restrict__ z1b,
                                             const float* __restrict__ b1, float* xt) {
  const int node = blockIdx.x * 4 + (threadIdx.x >> 6);
  const int lane = threadIdx.x & 63;
  const int idx = node * 64 + lane;
  float z = z1a[idx] + z1b[idx];
  float o = hyp_linear_chain(z, b1, lane, 64);
  xt[idx] = o;
}

// ===================== CSR build =====================
__global__ __launch_bounds__(256) void k_hist(const int* __restrict__ row, int* __restrict__ cnt) {
  int e = blockIdx.x * 256 + threadIdx.x;
  if (e < EE) atomicAdd(&cnt[row[e]], 1);
}

__global__ __launch_bounds__(1024) void k_scan(const int* __restrict__ cnt,
                                               int* __restrict__ rowptr, int* __restrict__ cur) {
  __shared__ int ssum[1024];
  const int tid = threadIdx.x;
  const int base = tid * 49;
  int s = 0;
  for (int j = 0; j < 49; ++j) {
    int i = base + j;
    if (i < NN) s += cnt[i];
  }
  ssum[tid] = s;
  __syncthreads();
  for (int off = 1; off < 1024; off <<= 1) {
    int v = (tid >= off) ? ssum[tid - off] : 0;
    __syncthreads();
    ssum[tid] += v;
    __syncthreads();
  }
  int run = ssum[tid] - s;
  for (int j = 0; j < 49; ++j) {
    int i = base + j;
    if (i < NN) {
      rowptr[i] = run;
      cur[i] = run;
      run += cnt[i];
    }
  }
  if (tid == 1023) rowptr[NN] = ssum[1023];
}

// scatter fused (col, ew) pairs — removes one indirection from the agg loops
__global__ __launch_bounds__(256) void k_scatter(const int* __restrict__ row,
                                                 const int* __restrict__ col,
                                                 const float* __restrict__ ew,
                                                 int* __restrict__ cur, uint2* __restrict__ ep) {
  int e = blockIdx.x * 256 + threadIdx.x;
  if (e < EE) {
    int p = atomicAdd(&cur[row[e]], 1);
    uint2 q;
    q.x = (unsigned int)col[e];
    q.y = __float_as_uint(ew[e]);
    ep[p] = q;
  }
}

// ===================== agg1 (gather, unroll-4) + chains + W2 ====
__global__ __launch_bounds__(256) void agg1_node2(const int* __restrict__ rowptr,
                                                  const uint2* __restrict__ ep,
                                                  const float* __restrict__ xt,
                                                  const float* __restrict__ W2,
                                                  const float* __restrict__ b2,
                                                  float* __restrict__ xt3) {
  const int node = blockIdx.x * 4 + (threadIdx.x >> 6);
  const int lane = threadIdx.x & 63;
  const int s0 = rowptr[node], s1 = rowptr[node + 1];
  float a0 = 0.f, a1 = 0.f, a2 = 0.f, a3 = 0.f;
  int p = s0;
  for (; p + 4 <= s1; p += 4) {
    uint2 q0 = ep[p], q1 = ep[p + 1], q2 = ep[p + 2], q3 = ep[p + 3];
    a0 = fmaf(__uint_as_float(q0.y), xt[(size_t)q0.x * 64 + lane], a0);
    a1 = fmaf(__uint_as_float(q1.y), xt[(size_t)q1.x * 64 + lane], a1);
    a2 = fmaf(__uint_as_float(q2.y), xt[(size_t)q2.x * 64 + lane], a2);
    a3 = fmaf(__uint_as_float(q3.y), xt[(size_t)q3.x * 64 + lane], a3);
  }
  for (; p < s1; ++p) {
    uint2 q = ep[p];
    a0 = fmaf(__uint_as_float(q.y), xt[(size_t)q.x * 64 + lane], a0);
  }
  float acc = (a0 + a1) + (a2 + a3);
  float xt2 = agg_act_chain(acc, lane, 64);
  float z2 = 0.f;
#pragma unroll
  for (int jj = 1; jj < 7; ++jj) {
    float wv = W2[jj * 64 + lane];
    float sjj = wsum(xt2 * wv);
    if (lane == jj) z2 = sjj;
  }
  float o = hyp_linear_chain(z2, b2, lane, 7);
  if (lane < 8) xt3[node * 8 + lane] = o;
}

// ===================== agg2 + final chain: 8 nodes per wave =====================
__global__ __launch_bounds__(256) void agg2_final(const int* __restrict__ rowptr,
                                                  const uint2* __restrict__ ep,
                                                  const float* __restrict__ xt3,
                                                  float* __restrict__ out) {
  const int node = blockIdx.x * 32 + (threadIdx.x >> 3);
  const int f = threadIdx.x & 7;
  const int nc = (node < NN) ? node : (NN - 1);
  const int s0 = rowptr[nc], s1 = rowptr[nc + 1];
  float a0 = 0.f, a1 = 0.f, a2 = 0.f, a3 = 0.f;
  int p = s0;
  for (; p + 4 <= s1; p += 4) {
    uint2 q0 = ep[p], q1 = ep[p + 1], q2 = ep[p + 2], q3 = ep[p + 3];
    a0 = fmaf(__uint_as_float(q0.y), xt3[(size_t)q0.x * 8 + f], a0);
    a1 = fmaf(__uint_as_float(q1.y), xt3[(size_t)q1.x * 8 + f], a1);
    a2 = fmaf(__uint_as_float(q2.y), xt3[(size_t)q2.x * 8 + f], a2);
    a3 = fmaf(__uint_as_float(q3.y), xt3[(size_t)q3.x * 8 + f], a3);
  }
  for (; p < s1; ++p) {
    uint2 q = ep[p];
    a0 = fmaf(__uint_as_float(q.y), xt3[(size_t)q.x * 8 + f], a0);
  }
  float acc = (a0 + a1) + (a2 + a3);
  float o = agg_act_chain8(acc, f);
  if (node < NN && f < 7) out[node * 7 + f] = o;
}

extern "C" void kernel_launch(void* const* d_in, const int* in_sizes, int n_in,
                              void* d_out, int out_size, void* d_ws, size_t ws_size,
                              hipStream_t stream) {
  const float* x = (const float*)d_in[0];
  const int* row = (const int*)d_in[1];
  const int* col = (const int*)d_in[2];
  const float* ew = (const float*)d_in[3];
  const float* W1 = (const float*)d_in[4];
  const float* b1 = (const float*)d_in[5];
  const float* W2 = (const float*)d_in[6];
  const float* b2 = (const float*)d_in[7];
  float* ws = (float*)d_ws;
  unsigned short* wfrag = (unsigned short*)(ws + WF_OFF);
  float* z1a = ws + Z1A_OFF;
  float* z1b = ws + Z1B_OFF;
  float* xt3 = ws + XT3_OFF;
  int* cnt = (int*)(ws + CNT_OFF);
  int* rowptr = (int*)(ws + ROWPTR_OFF);
  int* cur = (int*)(ws + CUR_OFF);
  uint2* ep = (uint2*)(ws + EP_OFF);
  float* out = (float*)d_out;

  // CSR build (independent of GEMM)
  hipMemsetAsync(cnt, 0, NN * sizeof(int), stream);
  k_hist<<<dim3(3125), dim3(256), 0, stream>>>(row, cnt);
  k_scan<<<dim3(1), dim3(1024), 0, stream>>>(cnt, rowptr, cur);
  k_scatter<<<dim3(3125), dim3(256), 0, stream>>>(row, col, ew, cur, ep);

  // layer 1 GEMM (MFMA, split-K=2)
  prep_wfrag<<<dim3(92), dim3(256), 0, stream>>>(W1, wfrag);
  gemm_mfma<<<dim3(391, 2), dim3(256), 0, stream>>>(x, wfrag, z1a);
  node1<<<dim3(12500), dim3(256), 0, stream>>>(z1a, z1b, b1, z1a);

  agg1_node2<<<dim3(12500), dim3(256), 0, stream>>>(rowptr, ep, z1a, W2, b2, xt3);
  agg2_final<<<dim3(1563), dim3(256), 0, stream>>>(rowptr, ep, xt3, out);
}